// Round 12
// baseline (130.240 us; speedup 1.0000x reference)
//
#include <hip/hip_runtime.h>
#include <hip/hip_bf16.h>

// MultiHeadCausalSelfAttention: B=2, N=4096, C=512, H=8, D=64, causal, fp32 in/out.
// Pipeline: cvt(fused) -> QKV GEMM (scatter Q, frag-layout K/V) -> attn(+merge) -> proj.
// R12: QBLK=16 (half the per-wave state), heavy tiles split-KV x2 -> 6144 one-wave
// blocks (HW backfill sustains occupancy); body math identical to proven R8/R11.

typedef __attribute__((ext_vector_type(8))) short s16x8;   // 8 bf16 = one MFMA A/B frag
typedef __attribute__((ext_vector_type(4))) float f32x4;   // one MFMA C/D frag

#define QSCALE 0.18033688011112042f  // D^-0.5 * log2(e), folded into Q

__device__ __forceinline__ ushort f2bf(float f) {
  unsigned u = __float_as_uint(f);
  u = (u + 0x7FFFu + ((u >> 16) & 1u)) >> 16;  // RNE
  return (ushort)u;
}

__device__ __forceinline__ unsigned cvt_pk_bf16(float a, float b) {
  unsigned r;
  asm("v_cvt_pk_bf16_f32 %0, %1, %2" : "=v"(r) : "v"(a), "v"(b));
  return r;  // low16 = bf16(a), high16 = bf16(b)
}

__device__ __forceinline__ float bflo(unsigned u) { return __uint_as_float(u << 16); }
__device__ __forceinline__ float bfhi(unsigned u) { return __uint_as_float(u & 0xffff0000u); }

// One fused cvt for x (1048576 float4), w_qkv (196608), w_proj (65536).
__global__ __launch_bounds__(256) void cvt_all(const float* __restrict__ x,
                                               const float* __restrict__ wq,
                                               const float* __restrict__ wp,
                                               ushort* __restrict__ xb,
                                               ushort* __restrict__ wqb,
                                               ushort* __restrict__ wpb) {
  int i = blockIdx.x * 256 + threadIdx.x;
  const float* src;
  ushort* dst;
  int off;
  if (i < 1048576) {
    src = x; dst = xb; off = i;
  } else if (i < 1245184) {
    src = wq; dst = wqb; off = i - 1048576;
  } else {
    src = wp; dst = wpb; off = i - 1245184;
  }
  float4 v = reinterpret_cast<const float4*>(src)[off];
  ushort4 o;
  o.x = f2bf(v.x); o.y = f2bf(v.y); o.z = f2bf(v.z); o.w = f2bf(v.w);
  reinterpret_cast<ushort4*>(dst)[off] = o;
}

// C = A[M,512] @ W[Nout,512]^T, bf16 MFMA, 128x128 tile, 4 waves (2x2), BK=32.
// Staging: global_load_lds width=16, source pre-swizzled (LDS dest linear).
// Single-buffer (proven). EPI 0: Q/K/V scatter. EPI 1: fp32 out + bias.
template <int EPI>
__global__ __launch_bounds__(256) void gemm_bt(const ushort* __restrict__ A,
                                               const ushort* __restrict__ W,
                                               ushort* __restrict__ q_ws,
                                               ushort* __restrict__ k_ws,
                                               ushort* __restrict__ vt_ws,
                                               float* __restrict__ outf,
                                               const float* __restrict__ bias) {
  __shared__ ushort As[128 * 32];
  __shared__ ushort Bs[128 * 32];
  const int tid = threadIdx.x;
  const int lane = tid & 63, wv = tid >> 6;
  const int wm = wv >> 1, wn = wv & 1;
  const int l15 = lane & 15, g = lane >> 4;
  const int tm = blockIdx.y * 128, tn = blockIdx.x * 128;

  f32x4 acc[4][4] = {};

  for (int k0 = 0; k0 < 512; k0 += 32) {
#pragma unroll
    for (int it = 0; it < 2; ++it) {
      int slot = it * 256 + tid;
      int row = slot >> 2;
      int ch = (slot & 3) ^ ((row >> 1) & 3);
      const int sb = (it * 256 + wv * 64) * 8;  // wave-uniform LDS base (ushorts)
      __builtin_amdgcn_global_load_lds(
          (const __attribute__((address_space(1))) void*)(A + (size_t)(tm + row) * 512 + k0 +
                                                          ch * 8),
          (__attribute__((address_space(3))) void*)(As + sb), 16, 0, 0);
      __builtin_amdgcn_global_load_lds(
          (const __attribute__((address_space(1))) void*)(W + (size_t)(tn + row) * 512 + k0 +
                                                          ch * 8),
          (__attribute__((address_space(3))) void*)(Bs + sb), 16, 0, 0);
    }
    __syncthreads();
    s16x8 af[4], bfr[4];
#pragma unroll
    for (int i = 0; i < 4; ++i) {
      int Ra = wm * 64 + i * 16 + l15;
      af[i] = reinterpret_cast<const s16x8*>(As)[Ra * 4 + (g ^ ((Ra >> 1) & 3))];
      int Rb = wn * 64 + i * 16 + l15;
      bfr[i] = reinterpret_cast<const s16x8*>(Bs)[Rb * 4 + (g ^ ((Rb >> 1) & 3))];
    }
#pragma unroll
    for (int mi = 0; mi < 4; ++mi)
#pragma unroll
      for (int ni = 0; ni < 4; ++ni)
        acc[mi][ni] =
            __builtin_amdgcn_mfma_f32_16x16x32_bf16(af[mi], bfr[ni], acc[mi][ni], 0, 0, 0);
    __syncthreads();
  }

  // C/D layout: col = lane&15, row = (lane>>4)*4 + reg   [measured m89/m91]
  const int rowb = tm + wm * 64 + g * 4;
  const int colb = tn + wn * 64 + l15;
#pragma unroll
  for (int mi = 0; mi < 4; ++mi) {
#pragma unroll
    for (int ni = 0; ni < 4; ++ni) {
      int r0 = rowb + mi * 16;
      int col = colb + ni * 16;
      if (EPI == 0) {
        int i3 = col >> 9, h = (col >> 6) & 7, d = col & 63;
        int b = r0 >> 12;
        int bh = b * 8 + h;
        if (i3 == 2) {
          int n0 = r0 & 4095;
          int kt = n0 >> 6, ce = (n0 >> 5) & 1, ge = (n0 >> 3) & 3, je = n0 & 7;
          int nbe = d >> 4, le = d & 15;
          ushort4 pk;
          pk.x = f2bf(acc[mi][ni][0]);
          pk.y = f2bf(acc[mi][ni][1]);
          pk.z = f2bf(acc[mi][ni][2]);
          pk.w = f2bf(acc[mi][ni][3]);
          *reinterpret_cast<ushort4*>(
              vt_ws + (((size_t)bh * 64 + kt) * 8 + nbe * 2 + ce) * 512 + (ge * 16 + le) * 8 +
              je) = pk;
        } else if (i3 == 1) {
          int ce = d >> 5, ge = (d >> 3) & 3, je = d & 7;
#pragma unroll
          for (int r = 0; r < 4; ++r) {
            int n = (r0 + r) & 4095;
            int kt = n >> 6, le = n & 15, nbe = (n >> 4) & 3;
            k_ws[(((size_t)bh * 64 + kt) * 8 + nbe * 2 + ce) * 512 + (ge * 16 + le) * 8 + je] =
                f2bf(acc[mi][ni][r]);
          }
        } else {
          int n0 = r0 & 4095;
#pragma unroll
          for (int r = 0; r < 4; ++r)
            q_ws[((size_t)bh * 4096 + (n0 + r)) * 64 + d] = f2bf(acc[mi][ni][r] * QSCALE);
        }
      } else {
#pragma unroll
        for (int r = 0; r < 4; ++r)
          outf[(size_t)(r0 + r) * 512 + col] = acc[mi][ni][r] + bias[col];
      }
    }
  }
}

// Flash attention, causal. 6144 x 64-thread (1-wave) blocks, QBLK=16.
// XCD-chunked: p = L&7 owns bh {2p, 2p+1}; LPT triples (heavy-lo, heavy-hi, light).
// qt in [0,256) (16-row tiles). Heavy (qt>=128) split-KV x2 -> bf16 partials + merge.
__global__ __launch_bounds__(64, 3) void attn_kernel(const ushort* __restrict__ Q,
                                                     const ushort* __restrict__ Kk,
                                                     const ushort* __restrict__ Vt,
                                                     ushort* __restrict__ O,
                                                     ushort* __restrict__ po,
                                                     float* __restrict__ ml) {
  __shared__ ushort P_lds[16 * 64];  // rows = 16 queries, cols = 64 keys (swizzled)
  const int lane = threadIdx.x & 63;
  const int l15 = lane & 15, g = lane >> 4;
  const int L = blockIdx.x;              // 0..6143
  const int p = L & 7, j2 = L >> 3;      // consecutive L round-robin XCDs -> p = XCD
  const int bh = p * 2 + (j2 & 1);       // each XCD: 2 bh only (K/V in its L2)
  const int i = j2 >> 1;                 // 0..383
  const int r = i / 3;                   // 0..127
  const int kind = i - r * 3;            // 0:heavy-lo 1:heavy-hi 2:light
  int qt, klo, khi, half = 0;
  bool partial;
  if (kind == 2) {
    qt = 127 - r;                        // light: qt in [0,128)
    partial = false;
    klo = 0;
    khi = qt >> 2;
  } else {
    qt = 255 - r;                        // heavy: qt in [128,256)
    partial = true;
    half = kind;
    const int ktm = qt >> 2;
    const int mid = (ktm + 2) >> 1;
    klo = kind ? mid : 0;
    khi = kind ? ktm : (mid - 1);
  }
  const int ktmax = qt >> 2;  // diagonal tile index (mask condition)
  const int qw = qt * 16;
  const size_t baseQ = (size_t)bh * 4096 * 64;

  // Q B-frags: query qw + l15, k-elems c*32 + g*8 + j
  s16x8 aq0, aq1;
  {
    const ushort* qp = Q + baseQ + (size_t)(qw + l15) * 64 + g * 8;
    aq0 = *reinterpret_cast<const s16x8*>(qp);
    aq1 = *reinterpret_cast<const s16x8*>(qp + 32);
  }

  f32x4 o[4] = {};
  float m = -1e30f;
  float l = 0.f;  // per-lane PARTIAL sum (reduced in epilogue)
  const int swz = (l15 & 7) << 3;  // XOR swizzle in ushort units (16B granule)
  const ushort* kb = Kk + ((size_t)bh * 64) * 4096 + lane * 8;
  const ushort* vb = Vt + ((size_t)bh * 64) * 4096 + lane * 8;

  s16x8 kfA[8], kfB[8];
#pragma unroll
  for (int t = 0; t < 8; ++t)
    kfA[t] = *reinterpret_cast<const s16x8*>(kb + (size_t)klo * 4096 + t * 512);

#define ATTN_STEP(KC, KN, KT)                                                             \
  do {                                                                                    \
    const ushort* vp = vb + (size_t)(KT) * 4096;                                          \
    s16x8 vf[8];                                                                          \
    _Pragma("unroll") for (int t = 0; t < 8; ++t)                                         \
        vf[t] = *reinterpret_cast<const s16x8*>(vp + t * 512);                            \
    const int knx = ((KT) >= khi) ? khi : ((KT) + 1);                                     \
    const ushort* kpn = kb + (size_t)knx * 4096;                                          \
    _Pragma("unroll") for (int t = 0; t < 8; ++t)                                         \
        KN[t] = *reinterpret_cast<const s16x8*>(kpn + t * 512);                           \
    f32x4 st[4] = {};                                                                     \
    __builtin_amdgcn_s_setprio(1);                                                        \
    _Pragma("unroll") for (int nb = 0; nb < 4; ++nb) {                                    \
      st[nb] = __builtin_amdgcn_mfma_f32_16x16x32_bf16(KC[nb * 2 + 0], aq0, st[nb],       \
                                                       0, 0, 0);                          \
      st[nb] = __builtin_amdgcn_mfma_f32_16x16x32_bf16(KC[nb * 2 + 1], aq1, st[nb],       \
                                                       0, 0, 0);                          \
    }                                                                                     \
    __builtin_amdgcn_s_setprio(0);                                                        \
    if ((KT) == ktmax) { /* diagonal: mask key > query */                                 \
      const int k0d = (KT) * 64;                                                          \
      _Pragma("unroll") for (int nb = 0; nb < 4; ++nb)                                    \
          _Pragma("unroll") for (int r2 = 0; r2 < 4; ++r2)                                \
              if (k0d + nb * 16 + g * 4 + r2 > qw + l15) st[nb][r2] = -1e30f;             \
    }                                                                                     \
    {                                                                                     \
      float a0 = fmaxf(fmaxf(st[0][0], st[0][1]), fmaxf(st[0][2], st[0][3]));             \
      float a1 = fmaxf(fmaxf(st[1][0], st[1][1]), fmaxf(st[1][2], st[1][3]));             \
      float a2 = fmaxf(fmaxf(st[2][0], st[2][1]), fmaxf(st[2][2], st[2][3]));             \
      float a3 = fmaxf(fmaxf(st[3][0], st[3][1]), fmaxf(st[3][2], st[3][3]));             \
      float pm = fmaxf(fmaxf(a0, a1), fmaxf(a2, a3)); /* lane-local max */                \
      if (!__all(pm - m <= 8.0f)) { /* rare: full reduce + rescale */                     \
        float pmf = fmaxf(pm, __shfl_xor(pm, 16));                                        \
        pmf = fmaxf(pmf, __shfl_xor(pmf, 32));                                            \
        const float mn = fmaxf(m, pmf);                                                   \
        const float al = __builtin_amdgcn_exp2f(m - mn);                                  \
        l *= al;                                                                          \
        m = mn;                                                                           \
        _Pragma("unroll") for (int nb = 0; nb < 4; ++nb)                                  \
            _Pragma("unroll") for (int r2 = 0; r2 < 4; ++r2) o[nb][r2] *= al;             \
      }                                                                                   \
      float rs = 0.f;                                                                     \
      _Pragma("unroll") for (int nb = 0; nb < 4; ++nb) {                                  \
        float p0 = __builtin_amdgcn_exp2f(st[nb][0] - m);                                 \
        float p1 = __builtin_amdgcn_exp2f(st[nb][1] - m);                                 \
        float p2 = __builtin_amdgcn_exp2f(st[nb][2] - m);                                 \
        float p3 = __builtin_amdgcn_exp2f(st[nb][3] - m);                                 \
        rs += (p0 + p1) + (p2 + p3);                                                      \
        uint2 w;                                                                          \
        w.x = cvt_pk_bf16(p0, p1);                                                        \
        w.y = cvt_pk_bf16(p2, p3);                                                        \
        *reinterpret_cast<uint2*>(P_lds + l15 * 64 + ((nb * 16 + g * 4) ^ swz)) = w;      \
      }                                                                                   \
      l += rs;                                                                            \
    }                                                                                     \
    s16x8 pa[2];                                                                          \
    _Pragma("unroll") for (int c = 0; c < 2; ++c)                                         \
        pa[c] = *reinterpret_cast<const s16x8*>(P_lds + l15 * 64 +                        \
                                                ((c * 32 + g * 8) ^ swz));                \
    __builtin_amdgcn_s_setprio(1);                                                        \
    _Pragma("unroll") for (int nb = 0; nb < 4; ++nb) {                                    \
      o[nb] = __builtin_amdgcn_mfma_f32_16x16x32_bf16(vf[nb * 2 + 0], pa[0], o[nb],       \
                                                      0, 0, 0);                           \
      o[nb] = __builtin_amdgcn_mfma_f32_16x16x32_bf16(vf[nb * 2 + 1], pa[1], o[nb],       \
                                                      0, 0, 0);                           \
    }                                                                                     \
    __builtin_amdgcn_s_setprio(0);                                                        \
  } while (0)

  int kt = klo;
  for (;;) {
    ATTN_STEP(kfA, kfB, kt);
    if (++kt > khi) break;
    ATTN_STEP(kfB, kfA, kt);
    if (++kt > khi) break;
  }
#undef ATTN_STEP

  // Reduce partial l across the 4 lane-groups (row sum per query l15).
  float lr = l;
  lr += __shfl_xor(lr, 16);
  lr += __shfl_xor(lr, 32);

  if (!partial) {
    // O^T: lane owns query qw + l15; d = nb*16 + g*4 + r2
    const int b = bh >> 3, h = bh & 7;
    const float linv = 1.0f / lr;
    const size_t rowo = (size_t)(b * 4096 + qw + l15) * 512 + h * 64;
#pragma unroll
    for (int nb = 0; nb < 4; ++nb) {
      uint2 pk;
      pk.x = cvt_pk_bf16(o[nb][0] * linv, o[nb][1] * linv);
      pk.y = cvt_pk_bf16(o[nb][2] * linv, o[nb][3] * linv);
      *reinterpret_cast<uint2*>(&O[rowo + nb * 16 + g * 4]) = pk;
    }
  } else {
    // Normalized bf16 partial O (16 rows x 64 d) + (m, l) per row.
    const int t2 = (bh * 128 + (qt - 128)) * 2 + half;
    const float linv = 1.0f / lr;
    const size_t pbase = ((size_t)t2 * 16 + l15) * 64;
#pragma unroll
    for (int nb = 0; nb < 4; ++nb) {
      uint2 pk;
      pk.x = cvt_pk_bf16(o[nb][0] * linv, o[nb][1] * linv);
      pk.y = cvt_pk_bf16(o[nb][2] * linv, o[nb][3] * linv);
      *reinterpret_cast<uint2*>(po + pbase + nb * 16 + g * 4) = pk;
    }
    if (g == 0) {
      float2 v;
      v.x = m;
      v.y = lr;
      *reinterpret_cast<float2*>(ml + ((size_t)t2 * 16 + l15) * 2) = v;
    }
  }
}

// Merge the two KV-halves of each heavy q-tile. 2048 blocks x 64 threads.
// Block = one 16-row tile; thread (row = tid&15, seg = tid>>4) merges 16 d values.
__global__ __launch_bounds__(64) void attn_merge(const ushort* __restrict__ po,
                                                 const float* __restrict__ ml,
                                                 ushort* __restrict__ O) {
  const int M = blockIdx.x, tid = threadIdx.x;
  const int p = M & 7, q2 = M >> 3;
  const int bh = p * 2 + (q2 & 1);
  const int qt = 128 + (q2 >> 1);
  const int t = bh * 128 + (qt - 128);
  const int row = tid & 15, seg = tid >> 4;  // 4 segs x 16 d
  const float2 ml0 = *reinterpret_cast<const float2*>(ml + ((size_t)(t * 2 + 0) * 16 + row) * 2);
  const float2 ml1 = *reinterpret_cast<const float2*>(ml + ((size_t)(t * 2 + 1) * 16 + row) * 2);
  const float ms = fmaxf(ml0.x, ml1.x);
  const float w0 = __builtin_amdgcn_exp2f(ml0.x - ms) * ml0.y;
  const float w1 = __builtin_amdgcn_exp2f(ml1.x - ms) * ml1.y;
  const float inv = 1.0f / (w0 + w1);
  const float c0 = w0 * inv, c1 = w1 * inv;
  const int b = bh >> 3, h = bh & 7;
  const size_t rowo = (size_t)(b * 4096 + qt * 16 + row) * 512 + h * 64 + seg * 16;
  const ushort* p0 = po + ((size_t)(t * 2 + 0) * 16 + row) * 64 + seg * 16;
  const ushort* p1 = po + ((size_t)(t * 2 + 1) * 16 + row) * 64 + seg * 16;
#pragma unroll
  for (int j = 0; j < 2; ++j) {
    uint4 a = reinterpret_cast<const uint4*>(p0)[j];
    uint4 bb = reinterpret_cast<const uint4*>(p1)[j];
    uint4 out;
    out.x = cvt_pk_bf16(c0 * bflo(a.x) + c1 * bflo(bb.x), c0 * bfhi(a.x) + c1 * bfhi(bb.x));
    out.y = cvt_pk_bf16(c0 * bflo(a.y) + c1 * bflo(bb.y), c0 * bfhi(a.y) + c1 * bfhi(bb.y));
    out.z = cvt_pk_bf16(c0 * bflo(a.z) + c1 * bflo(bb.z), c0 * bfhi(a.z) + c1 * bfhi(bb.z));
    out.w = cvt_pk_bf16(c0 * bflo(a.w) + c1 * bflo(bb.w), c0 * bfhi(a.w) + c1 * bfhi(bb.w));
    reinterpret_cast<uint4*>(&O[rowo])[j] = out;
  }
}

extern "C" void kernel_launch(void* const* d_in, const int* in_sizes, int n_in,
                              void* d_out, int out_size, void* d_ws, size_t ws_size,
                              hipStream_t stream) {
  const float* x = (const float*)d_in[0];       // [2,4096,512]
  const float* w_qkv = (const float*)d_in[1];   // [1536,512]
  const float* w_proj = (const float*)d_in[2];  // [512,512]
  const float* b_proj = (const float*)d_in[3];  // [512]
  float* out = (float*)d_out;                   // [2,4096,512]

  ushort* xb = (ushort*)d_ws;                       // 8192*512   (reused as po)
  ushort* wqkvb = xb + (size_t)8192 * 512;          // 1536*512   (reused as ml)
  ushort* wprojb = wqkvb + (size_t)1536 * 512;      // 512*512
  ushort* qws = wprojb + (size_t)512 * 512;         // 16*4096*64
  ushort* kws = qws + (size_t)16 * 4096 * 64;
  ushort* vtws = kws + (size_t)16 * 4096 * 64;
  ushort* ows = vtws + (size_t)16 * 4096 * 64;      // 8192*512

  cvt_all<<<5120, 256, 0, stream>>>(x, w_qkv, w_proj, xb, wqkvb, wprojb);

  gemm_bt<0><<<dim3(12, 64), 256, 0, stream>>>(xb, wqkvb, qws, kws, vtws, nullptr, nullptr);

  // xb / wqkvb are dead now -> reuse as split-KV partial buffers.
  // po: 16 bh x 128 heavy tiles x 2 halves x (16 rows x 64 d) bf16 = 8.4 MB (= xb size)
  ushort* po = xb;
  float* ml = (float*)wqkvb;   // 4096 parts x 16 rows x {m,l} f32 = 512 KB

  attn_kernel<<<6144, 64, 0, stream>>>(qws, kws, vtws, ows, po, ml);
  attn_merge<<<2048, 64, 0, stream>>>(po, ml, ows);

  gemm_bt<1><<<dim3(4, 64), 256, 0, stream>>>(ows, wprojb, nullptr, nullptr, nullptr, out,
                                              b_proj);
}

// Round 13
// 110.252 us; speedup vs baseline: 1.1813x; 1.1813x over previous
//
#include <hip/hip_runtime.h>
#include <hip/hip_bf16.h>

// MultiHeadCausalSelfAttention: B=2, N=4096, C=512, H=8, D=64, causal, fp32 in/out.
// Pipeline: cvt(fused) -> QKV GEMM (scatter Q, frag-layout K/V) -> attn(+merge) -> proj.
// R13: attn reverted to R11 (QBLK=32, 67us proven; R12 QBLK=16 regressed);
//      GEMMs get 2-phase double-buffer (R10 bisect cleared it: attn was the bug).

typedef __attribute__((ext_vector_type(8))) short s16x8;   // 8 bf16 = one MFMA A/B frag
typedef __attribute__((ext_vector_type(4))) float f32x4;   // one MFMA C/D frag

#define QSCALE 0.18033688011112042f  // D^-0.5 * log2(e), folded into Q

__device__ __forceinline__ ushort f2bf(float f) {
  unsigned u = __float_as_uint(f);
  u = (u + 0x7FFFu + ((u >> 16) & 1u)) >> 16;  // RNE
  return (ushort)u;
}

__device__ __forceinline__ unsigned cvt_pk_bf16(float a, float b) {
  unsigned r;
  asm("v_cvt_pk_bf16_f32 %0, %1, %2" : "=v"(r) : "v"(a), "v"(b));
  return r;  // low16 = bf16(a), high16 = bf16(b)
}

__device__ __forceinline__ float bflo(unsigned u) { return __uint_as_float(u << 16); }
__device__ __forceinline__ float bfhi(unsigned u) { return __uint_as_float(u & 0xffff0000u); }

// One fused cvt for x (1048576 float4), w_qkv (196608), w_proj (65536).
__global__ __launch_bounds__(256) void cvt_all(const float* __restrict__ x,
                                               const float* __restrict__ wq,
                                               const float* __restrict__ wp,
                                               ushort* __restrict__ xb,
                                               ushort* __restrict__ wqb,
                                               ushort* __restrict__ wpb) {
  int i = blockIdx.x * 256 + threadIdx.x;
  const float* src;
  ushort* dst;
  int off;
  if (i < 1048576) {
    src = x; dst = xb; off = i;
  } else if (i < 1245184) {
    src = wq; dst = wqb; off = i - 1048576;
  } else {
    src = wp; dst = wpb; off = i - 1245184;
  }
  float4 v = reinterpret_cast<const float4*>(src)[off];
  ushort4 o;
  o.x = f2bf(v.x); o.y = f2bf(v.y); o.z = f2bf(v.z); o.w = f2bf(v.w);
  reinterpret_cast<ushort4*>(dst)[off] = o;
}

// C = A[M,512] @ W[Nout,512]^T, bf16 MFMA, 128x128 tile, 4 waves (2x2), BK=32.
// 2-phase double-buffer: STAGE(t+1) issued before compute(t), one barrier/iter.
// Staging: global_load_lds width=16, source pre-swizzled (LDS dest linear).
// EPI 0: Q/K/V scatter. EPI 1: fp32 out + bias.
template <int EPI>
__global__ __launch_bounds__(256) void gemm_bt(const ushort* __restrict__ A,
                                               const ushort* __restrict__ W,
                                               ushort* __restrict__ q_ws,
                                               ushort* __restrict__ k_ws,
                                               ushort* __restrict__ vt_ws,
                                               float* __restrict__ outf,
                                               const float* __restrict__ bias) {
  __shared__ ushort As[2][128 * 32];
  __shared__ ushort Bs[2][128 * 32];
  const int tid = threadIdx.x;
  const int lane = tid & 63, wv = tid >> 6;
  const int wm = wv >> 1, wn = wv & 1;
  const int l15 = lane & 15, g = lane >> 4;
  const int tm = blockIdx.y * 128, tn = blockIdx.x * 128;

  f32x4 acc[4][4] = {};

#define GSTAGE(BUF, K0)                                                                    \
  do {                                                                                     \
    _Pragma("unroll") for (int it = 0; it < 2; ++it) {                                     \
      int slot = it * 256 + tid;                                                           \
      int row = slot >> 2;                                                                 \
      int ch = (slot & 3) ^ ((row >> 1) & 3);                                              \
      const int sb = (it * 256 + wv * 64) * 8; /* wave-uniform LDS base (ushorts) */       \
      __builtin_amdgcn_global_load_lds(                                                    \
          (const __attribute__((address_space(1))) void*)(A + (size_t)(tm + row) * 512 +   \
                                                          (K0) + ch * 8),                  \
          (__attribute__((address_space(3))) void*)(&As[BUF][0] + sb), 16, 0, 0);          \
      __builtin_amdgcn_global_load_lds(                                                    \
          (const __attribute__((address_space(1))) void*)(W + (size_t)(tn + row) * 512 +   \
                                                          (K0) + ch * 8),                  \
          (__attribute__((address_space(3))) void*)(&Bs[BUF][0] + sb), 16, 0, 0);          \
    }                                                                                      \
  } while (0)

  GSTAGE(0, 0);
  __syncthreads();  // drain staged loads for buffer 0
  int cur = 0;
  for (int t = 0; t < 16; ++t) {
    if (t < 15) GSTAGE(cur ^ 1, (t + 1) * 32);  // next tile in flight during compute
    s16x8 af[4], bfr[4];
#pragma unroll
    for (int i = 0; i < 4; ++i) {
      int Ra = wm * 64 + i * 16 + l15;
      af[i] = reinterpret_cast<const s16x8*>(&As[cur][0])[Ra * 4 + (g ^ ((Ra >> 1) & 3))];
      int Rb = wn * 64 + i * 16 + l15;
      bfr[i] = reinterpret_cast<const s16x8*>(&Bs[cur][0])[Rb * 4 + (g ^ ((Rb >> 1) & 3))];
    }
#pragma unroll
    for (int mi = 0; mi < 4; ++mi)
#pragma unroll
      for (int ni = 0; ni < 4; ++ni)
        acc[mi][ni] =
            __builtin_amdgcn_mfma_f32_16x16x32_bf16(af[mi], bfr[ni], acc[mi][ni], 0, 0, 0);
    __syncthreads();  // drains vmcnt (staged loads) + lgkm; both buffers safe
    cur ^= 1;
  }
#undef GSTAGE

  // C/D layout: col = lane&15, row = (lane>>4)*4 + reg   [measured m89/m91]
  const int rowb = tm + wm * 64 + g * 4;
  const int colb = tn + wn * 64 + l15;
#pragma unroll
  for (int mi = 0; mi < 4; ++mi) {
#pragma unroll
    for (int ni = 0; ni < 4; ++ni) {
      int r0 = rowb + mi * 16;
      int col = colb + ni * 16;
      if (EPI == 0) {
        int i3 = col >> 9, h = (col >> 6) & 7, d = col & 63;
        int b = r0 >> 12;
        int bh = b * 8 + h;
        if (i3 == 2) {
          int n0 = r0 & 4095;
          int kt = n0 >> 6, ce = (n0 >> 5) & 1, ge = (n0 >> 3) & 3, je = n0 & 7;
          int nbe = d >> 4, le = d & 15;
          ushort4 pk;
          pk.x = f2bf(acc[mi][ni][0]);
          pk.y = f2bf(acc[mi][ni][1]);
          pk.z = f2bf(acc[mi][ni][2]);
          pk.w = f2bf(acc[mi][ni][3]);
          *reinterpret_cast<ushort4*>(
              vt_ws + (((size_t)bh * 64 + kt) * 8 + nbe * 2 + ce) * 512 + (ge * 16 + le) * 8 +
              je) = pk;
        } else if (i3 == 1) {
          int ce = d >> 5, ge = (d >> 3) & 3, je = d & 7;
#pragma unroll
          for (int r = 0; r < 4; ++r) {
            int n = (r0 + r) & 4095;
            int kt = n >> 6, le = n & 15, nbe = (n >> 4) & 3;
            k_ws[(((size_t)bh * 64 + kt) * 8 + nbe * 2 + ce) * 512 + (ge * 16 + le) * 8 + je] =
                f2bf(acc[mi][ni][r]);
          }
        } else {
          int n0 = r0 & 4095;
#pragma unroll
          for (int r = 0; r < 4; ++r)
            q_ws[((size_t)bh * 4096 + (n0 + r)) * 64 + d] = f2bf(acc[mi][ni][r] * QSCALE);
        }
      } else {
#pragma unroll
        for (int r = 0; r < 4; ++r)
          outf[(size_t)(r0 + r) * 512 + col] = acc[mi][ni][r] + bias[col];
      }
    }
  }
}

// Flash attention, causal. 3072 x 64-thread (1-wave) blocks. (R11 proven body.)
// XCD-chunked: p = L&7 owns bh {2p, 2p+1}; LPT triples (heavy-lo, heavy-hi, light).
// Heavy (qt>=64) split-KV x2 -> bf16 partials + merge. Light store direct.
__global__ __launch_bounds__(64, 2) void attn_kernel(const ushort* __restrict__ Q,
                                                     const ushort* __restrict__ Kk,
                                                     const ushort* __restrict__ Vt,
                                                     ushort* __restrict__ O,
                                                     ushort* __restrict__ po,
                                                     float* __restrict__ ml) {
  __shared__ ushort P_lds[32 * 64];  // rows = 32 queries, cols = 64 keys (swizzled)
  const int lane = threadIdx.x & 63;
  const int l15 = lane & 15, g = lane >> 4;
  const int L = blockIdx.x;              // 0..3071
  const int p = L & 7, j2 = L >> 3;      // consecutive L round-robin XCDs -> p = XCD
  const int bh = p * 2 + (j2 & 1);       // each XCD: 2 bh only (K/V in its L2)
  const int i = j2 >> 1;                 // 0..191
  const int r = i / 3;                   // 0..63
  const int kind = i - r * 3;            // 0:heavy-lo 1:heavy-hi 2:light
  int qt, klo, khi, half = 0;
  bool partial;
  if (kind == 2) {
    qt = 63 - r;
    partial = false;
    klo = 0;
    khi = qt >> 1;
  } else {
    qt = 127 - r;
    partial = true;
    half = kind;
    const int ktm = qt >> 1;
    const int mid = (ktm + 2) >> 1;
    klo = kind ? mid : 0;
    khi = kind ? ktm : (mid - 1);
  }
  const int ktmax = qt >> 1;  // diagonal tile index (mask condition)
  const int qw = qt * 32;
  const size_t baseQ = (size_t)bh * 4096 * 64;

  // Q B-frags: sub s -> query qw + s*16 + l15, k-elems c*32 + g*8 + j
  s16x8 aq[2][2];
#pragma unroll
  for (int s = 0; s < 2; ++s) {
    const ushort* qp = Q + baseQ + (size_t)(qw + s * 16 + l15) * 64 + g * 8;
    aq[s][0] = *reinterpret_cast<const s16x8*>(qp);
    aq[s][1] = *reinterpret_cast<const s16x8*>(qp + 32);
  }

  f32x4 o[2][4] = {};
  float m[2] = {-1e30f, -1e30f};
  float l[2] = {0.f, 0.f};  // per-lane PARTIAL sums (reduced in epilogue)
  const int swz = (l15 & 7) << 3;  // XOR swizzle in ushort units (16B granule)
  const ushort* kb = Kk + ((size_t)bh * 64) * 4096 + lane * 8;
  const ushort* vb = Vt + ((size_t)bh * 64) * 4096 + lane * 8;

  s16x8 kfA[8], kfB[8];
#pragma unroll
  for (int t = 0; t < 8; ++t)
    kfA[t] = *reinterpret_cast<const s16x8*>(kb + (size_t)klo * 4096 + t * 512);

#define ATTN_STEP(KC, KN, KT)                                                             \
  do {                                                                                    \
    const ushort* vp = vb + (size_t)(KT) * 4096;                                          \
    s16x8 vf[8];                                                                          \
    _Pragma("unroll") for (int t = 0; t < 8; ++t)                                         \
        vf[t] = *reinterpret_cast<const s16x8*>(vp + t * 512);                            \
    const int knx = ((KT) >= khi) ? khi : ((KT) + 1);                                     \
    const ushort* kpn = kb + (size_t)knx * 4096;                                          \
    _Pragma("unroll") for (int t = 0; t < 8; ++t)                                         \
        KN[t] = *reinterpret_cast<const s16x8*>(kpn + t * 512);                           \
    f32x4 st[2][4] = {};                                                                  \
    __builtin_amdgcn_s_setprio(1);                                                        \
    _Pragma("unroll") for (int nb = 0; nb < 4; ++nb) {                                    \
      _Pragma("unroll") for (int s = 0; s < 2; ++s) {                                     \
        st[s][nb] = __builtin_amdgcn_mfma_f32_16x16x32_bf16(KC[nb * 2 + 0], aq[s][0],     \
                                                            st[s][nb], 0, 0, 0);         \
        st[s][nb] = __builtin_amdgcn_mfma_f32_16x16x32_bf16(KC[nb * 2 + 1], aq[s][1],     \
                                                            st[s][nb], 0, 0, 0);         \
      }                                                                                   \
    }                                                                                     \
    __builtin_amdgcn_s_setprio(0);                                                        \
    if ((KT) == ktmax) { /* diagonal: mask key > query */                                 \
      const int k0d = (KT) * 64;                                                          \
      _Pragma("unroll") for (int s = 0; s < 2; ++s)                                       \
          _Pragma("unroll") for (int nb = 0; nb < 4; ++nb)                                \
              _Pragma("unroll") for (int r2 = 0; r2 < 4; ++r2)                            \
                  if (k0d + nb * 16 + g * 4 + r2 > qw + s * 16 + l15)                     \
                    st[s][nb][r2] = -1e30f;                                               \
    }                                                                                     \
    _Pragma("unroll") for (int s = 0; s < 2; ++s) {                                       \
      float a0 = fmaxf(fmaxf(st[s][0][0], st[s][0][1]), fmaxf(st[s][0][2], st[s][0][3])); \
      float a1 = fmaxf(fmaxf(st[s][1][0], st[s][1][1]), fmaxf(st[s][1][2], st[s][1][3])); \
      float a2 = fmaxf(fmaxf(st[s][2][0], st[s][2][1]), fmaxf(st[s][2][2], st[s][2][3])); \
      float a3 = fmaxf(fmaxf(st[s][3][0], st[s][3][1]), fmaxf(st[s][3][2], st[s][3][3])); \
      float pm = fmaxf(fmaxf(a0, a1), fmaxf(a2, a3)); /* lane-local max */                \
      if (!__all(pm - m[s] <= 8.0f)) { /* rare: full reduce + rescale */                  \
        float pmf = fmaxf(pm, __shfl_xor(pm, 16));                                        \
        pmf = fmaxf(pmf, __shfl_xor(pmf, 32));                                            \
        const float mn = fmaxf(m[s], pmf);                                                \
        const float al = __builtin_amdgcn_exp2f(m[s] - mn);                               \
        l[s] *= al;                                                                       \
        m[s] = mn;                                                                        \
        _Pragma("unroll") for (int nb = 0; nb < 4; ++nb)                                  \
            _Pragma("unroll") for (int r2 = 0; r2 < 4; ++r2) o[s][nb][r2] *= al;          \
      }                                                                                   \
      float rs = 0.f;                                                                     \
      _Pragma("unroll") for (int nb = 0; nb < 4; ++nb) {                                  \
        float p0 = __builtin_amdgcn_exp2f(st[s][nb][0] - m[s]);                           \
        float p1 = __builtin_amdgcn_exp2f(st[s][nb][1] - m[s]);                           \
        float p2 = __builtin_amdgcn_exp2f(st[s][nb][2] - m[s]);                           \
        float p3 = __builtin_amdgcn_exp2f(st[s][nb][3] - m[s]);                           \
        rs += (p0 + p1) + (p2 + p3);                                                      \
        uint2 w;                                                                          \
        w.x = cvt_pk_bf16(p0, p1);                                                        \
        w.y = cvt_pk_bf16(p2, p3);                                                        \
        *reinterpret_cast<uint2*>(P_lds + (s * 16 + l15) * 64 +                           \
                                  ((nb * 16 + g * 4) ^ swz)) = w;                         \
      }                                                                                   \
      l[s] += rs;                                                                         \
    }                                                                                     \
    s16x8 pa[2][2];                                                                       \
    _Pragma("unroll") for (int s = 0; s < 2; ++s)                                         \
        _Pragma("unroll") for (int c = 0; c < 2; ++c)                                     \
            pa[s][c] = *reinterpret_cast<const s16x8*>(P_lds + (s * 16 + l15) * 64 +      \
                                                       ((c * 32 + g * 8) ^ swz));         \
    __builtin_amdgcn_s_setprio(1);                                                        \
    _Pragma("unroll") for (int nb = 0; nb < 4; ++nb) {                                    \
      _Pragma("unroll") for (int s = 0; s < 2; ++s) {                                     \
        o[s][nb] = __builtin_amdgcn_mfma_f32_16x16x32_bf16(vf[nb * 2 + 0], pa[s][0],      \
                                                           o[s][nb], 0, 0, 0);            \
        o[s][nb] = __builtin_amdgcn_mfma_f32_16x16x32_bf16(vf[nb * 2 + 1], pa[s][1],      \
                                                           o[s][nb], 0, 0, 0);            \
      }                                                                                   \
    }                                                                                     \
    __builtin_amdgcn_s_setprio(0);                                                        \
  } while (0)

  int kt = klo;
  for (;;) {
    ATTN_STEP(kfA, kfB, kt);
    if (++kt > khi) break;
    ATTN_STEP(kfB, kfA, kt);
    if (++kt > khi) break;
  }
#undef ATTN_STEP

  // Reduce partial l across the 4 lane-groups (row sum per query l15).
  float lr[2];
#pragma unroll
  for (int s = 0; s < 2; ++s) {
    float ls = l[s];
    ls += __shfl_xor(ls, 16);
    ls += __shfl_xor(ls, 32);
    lr[s] = ls;
  }

  if (!partial) {
    // O^T: lane owns query qw + s*16 + l15; d = nb*16 + g*4 + r2
    const int b = bh >> 3, h = bh & 7;
#pragma unroll
    for (int s = 0; s < 2; ++s) {
      const float linv = 1.0f / lr[s];
      const size_t rowo = (size_t)(b * 4096 + qw + s * 16 + l15) * 512 + h * 64;
#pragma unroll
      for (int nb = 0; nb < 4; ++nb) {
        uint2 pk;
        pk.x = cvt_pk_bf16(o[s][nb][0] * linv, o[s][nb][1] * linv);
        pk.y = cvt_pk_bf16(o[s][nb][2] * linv, o[s][nb][3] * linv);
        *reinterpret_cast<uint2*>(&O[rowo + nb * 16 + g * 4]) = pk;
      }
    }
  } else {
    // Normalized bf16 partial O + (m, l) per row.
    const int t2 = (bh * 64 + (qt - 64)) * 2 + half;
#pragma unroll
    for (int s = 0; s < 2; ++s) {
      const float linv = 1.0f / lr[s];
      const int row = s * 16 + l15;
      const size_t pbase = ((size_t)t2 * 32 + row) * 64;
#pragma unroll
      for (int nb = 0; nb < 4; ++nb) {
        uint2 pk;
        pk.x = cvt_pk_bf16(o[s][nb][0] * linv, o[s][nb][1] * linv);
        pk.y = cvt_pk_bf16(o[s][nb][2] * linv, o[s][nb][3] * linv);
        *reinterpret_cast<uint2*>(po + pbase + nb * 16 + g * 4) = pk;
      }
      if (g == 0) {
        float2 v;
        v.x = m[s];
        v.y = lr[s];
        *reinterpret_cast<float2*>(ml + ((size_t)t2 * 32 + row) * 2) = v;
      }
    }
  }
}

// Merge the two KV-halves of each heavy q-tile. 1024 blocks x 64 threads.
__global__ __launch_bounds__(64) void attn_merge(const ushort* __restrict__ po,
                                                 const float* __restrict__ ml,
                                                 ushort* __restrict__ O) {
  const int L = blockIdx.x, tid = threadIdx.x;
  const int p = L & 7, q2 = L >> 3;
  const int bh = p * 2 + (q2 & 1);
  const int qt = 64 + (q2 >> 1);
  const int t = bh * 64 + (qt - 64);
  const int row = tid >> 1, dh = (tid & 1) * 32;
  const float2 ml0 = *reinterpret_cast<const float2*>(ml + ((size_t)(t * 2 + 0) * 32 + row) * 2);
  const float2 ml1 = *reinterpret_cast<const float2*>(ml + ((size_t)(t * 2 + 1) * 32 + row) * 2);
  const float ms = fmaxf(ml0.x, ml1.x);
  const float w0 = __builtin_amdgcn_exp2f(ml0.x - ms) * ml0.y;
  const float w1 = __builtin_amdgcn_exp2f(ml1.x - ms) * ml1.y;
  const float inv = 1.0f / (w0 + w1);
  const float c0 = w0 * inv, c1 = w1 * inv;
  const int b = bh >> 3, h = bh & 7;
  const size_t rowo = (size_t)(b * 4096 + qt * 32 + row) * 512 + h * 64 + dh;
  const ushort* p0 = po + ((size_t)(t * 2 + 0) * 32 + row) * 64 + dh;
  const ushort* p1 = po + ((size_t)(t * 2 + 1) * 32 + row) * 64 + dh;
#pragma unroll
  for (int j = 0; j < 4; ++j) {
    uint4 a = reinterpret_cast<const uint4*>(p0)[j];
    uint4 bb = reinterpret_cast<const uint4*>(p1)[j];
    uint4 out;
    out.x = cvt_pk_bf16(c0 * bflo(a.x) + c1 * bflo(bb.x), c0 * bfhi(a.x) + c1 * bfhi(bb.x));
    out.y = cvt_pk_bf16(c0 * bflo(a.y) + c1 * bflo(bb.y), c0 * bfhi(a.y) + c1 * bfhi(bb.y));
    out.z = cvt_pk_bf16(c0 * bflo(a.z) + c1 * bflo(bb.z), c0 * bfhi(a.z) + c1 * bfhi(bb.z));
    out.w = cvt_pk_bf16(c0 * bflo(a.w) + c1 * bflo(bb.w), c0 * bfhi(a.w) + c1 * bfhi(bb.w));
    reinterpret_cast<uint4*>(&O[rowo])[j] = out;
  }
}

extern "C" void kernel_launch(void* const* d_in, const int* in_sizes, int n_in,
                              void* d_out, int out_size, void* d_ws, size_t ws_size,
                              hipStream_t stream) {
  const float* x = (const float*)d_in[0];       // [2,4096,512]
  const float* w_qkv = (const float*)d_in[1];   // [1536,512]
  const float* w_proj = (const float*)d_in[2];  // [512,512]
  const float* b_proj = (const float*)d_in[3];  // [512]
  float* out = (float*)d_out;                   // [2,4096,512]

  ushort* xb = (ushort*)d_ws;                       // 8192*512   (reused as po)
  ushort* wqkvb = xb + (size_t)8192 * 512;          // 1536*512   (reused as ml)
  ushort* wprojb = wqkvb + (size_t)1536 * 512;      // 512*512
  ushort* qws = wprojb + (size_t)512 * 512;         // 16*4096*64
  ushort* kws = qws + (size_t)16 * 4096 * 64;
  ushort* vtws = kws + (size_t)16 * 4096 * 64;
  ushort* ows = vtws + (size_t)16 * 4096 * 64;      // 8192*512

  cvt_all<<<5120, 256, 0, stream>>>(x, w_qkv, w_proj, xb, wqkvb, wprojb);

  gemm_bt<0><<<dim3(12, 64), 256, 0, stream>>>(xb, wqkvb, qws, kws, vtws, nullptr, nullptr);

  // xb / wqkvb are dead now -> reuse as split-KV partial buffers.
  ushort* po = xb;             // 1024 tiles x 2 halves x 32 rows x 64 d (bf16)
  float* ml = (float*)wqkvb;   // 1024 x 2 x 32 x {m,l} f32

  attn_kernel<<<3072, 64, 0, stream>>>(qws, kws, vtws, ows, po, ml);
  attn_merge<<<1024, 64, 0, stream>>>(po, ml, ows);

  gemm_bt<1><<<dim3(4, 64), 256, 0, stream>>>(ows, wprojb, nullptr, nullptr, nullptr, out,
                                              b_proj);
}